// Round 5
// baseline (5434.945 us; speedup 1.0000x reference)
//
#include <hip/hip_runtime.h>

#define HID   1024
#define NIN   128
#define BSZ   64
#define SLEN  512
#define KTOT  1152   // 1024 (W_hh) + 128 (W_ih)
#define NBLK  64
#define NOUT  128

typedef short          bf16x8 __attribute__((ext_vector_type(8)));
typedef unsigned short us8    __attribute__((ext_vector_type(8)));
typedef float          f32x4  __attribute__((ext_vector_type(4)));
typedef unsigned long long u64;

__device__ __forceinline__ unsigned short rne_bf16(float f) {
    unsigned int u = __builtin_bit_cast(unsigned int, f);
    u += 0x7FFFu + ((u >> 16) & 1u);
    return (unsigned short)(u >> 16);
}
__device__ __forceinline__ float bf2f(unsigned short h) {
    unsigned int u = ((unsigned int)h) << 16;
    return __builtin_bit_cast(float, u);
}

// ws layout (ushort units):
//  Whi[1024*1152] | Wlo[1024*1152] | hA[131072] | hB[131072]
//  | hfp[64K floats] | mlp[64K floats] | sig[512*64+64 uints]
// h buffers interleaved: [b][k/8][8 hi | 8 lo]  (hi/lo share a 32B line)
#define OFF_WLO 1179648
#define OFF_H0  2359296
#define OFF_H1  2490368
#define OFF_F32 2621440
#define OFF_SIG 2883584
#define SIG_N   (SLEN * 64 + 64)

__global__ void __launch_bounds__(256) prep(
    const float* __restrict__ W_ih, const float* __restrict__ W_hh,
    const float* __restrict__ h0, unsigned short* __restrict__ wsu)
{
    const int g = blockIdx.x * 256 + threadIdx.x;
    if (g < SIG_N) ((unsigned*)(wsu + OFF_SIG))[g] = 0u;
    if (g < 1024 * KTOT) {
        const int j = g / KTOT;
        const int k = g - j * KTOT;
        const float v = (k < HID) ? W_hh[j * HID + k] : W_ih[j * NIN + (k - HID)];
        const unsigned short hi = rne_bf16(v);
        wsu[g] = hi;
        wsu[OFF_WLO + g] = rne_bf16(v - bf2f(hi));
    } else if (g < 1024 * KTOT + 65536) {
        const int e = g - 1024 * KTOT;
        const int b = e >> 10, k = e & 1023;
        const float v = h0[e];
        const unsigned short hi = rne_bf16(v);
        const int base = OFF_H0 + b * 2048 + ((k >> 3) << 4) + (k & 7);
        wsu[base] = hi;
        wsu[base + 8] = rne_bf16(v - bf2f(hi));
    }
}

// 64 blocks = 32 j-tiles x 2 batch-halves; 512 threads = 8 waves:
// wave -> (kc = wave&3 K-quarter, m = wave>>2 M-subtile of 16 rows).
// W slice (hi+lo) XOR-swizzled in LDS. h ping-pong + sig flags accessed ONLY
// via agent-scope relaxed atomics (sc0/sc1, LLC-coherent) -> NO per-step
// fences, no L2 invalidate/writeback. Fences only at the two head handoffs.
__global__ void __launch_bounds__(512, 2) rnn_mfma(
    const float* __restrict__ x,
    const float* __restrict__ b_ih, const float* __restrict__ b_hh,
    const float* __restrict__ W1,   const float* __restrict__ b1,
    const float* __restrict__ W2,   const float* __restrict__ b2,
    float* __restrict__ out, unsigned short* __restrict__ wsu)
{
    const int tid  = threadIdx.x, bid = blockIdx.x;
    const int lane = tid & 63, wave = tid >> 6;
    const int lr = lane & 15, lg = lane >> 4;
    const int kc = wave & 3, m = wave >> 2;
    const int jb = bid >> 1, bh = bid & 1;
    const int j0 = jb * 32;

    const unsigned short* __restrict__ Whi = wsu;
    const unsigned short* __restrict__ Wlo = wsu + OFF_WLO;
    unsigned short* hA = wsu + OFF_H0;
    unsigned short* hB = wsu + OFF_H1;
    float* hfp = (float*)(wsu + OFF_F32);
    float* mlp = hfp + 65536;
    unsigned* sig = (unsigned*)(wsu + OFF_SIG);

    __shared__ unsigned short sW[2 * 32 * 1152];   // [hi/lo][row 0..31][k], XOR-swizzled
    __shared__ float red[2][32][33];

    // ---- stage W slice with T2 XOR swizzle: phys_c8 = c8 ^ (row&7) ----
    for (int e = tid; e < 32 * (KTOT / 8); e += 512) {
        const int row = e / (KTOT / 8), c8 = e - row * (KTOT / 8);
        const int pc8 = c8 ^ (row & 7);
        *(us8*)&sW[row * KTOT + pc8 * 8] =
            *(const us8*)(Whi + (size_t)(j0 + row) * KTOT + c8 * 8);
        *(us8*)&sW[32 * KTOT + row * KTOT + pc8 * 8] =
            *(const us8*)(Wlo + (size_t)(j0 + row) * KTOT + c8 * 8);
    }
    // reducer mapping: one batch row, two adjacent j per thread (u32 packs)
    const int b0 = tid >> 4;            // 0..31
    const int jp = tid & 15;            // 0..15
    const int jl0 = jp * 2;
    const int jg0 = j0 + jl0;
    const float bias0 = b_ih[jg0] + b_hh[jg0];
    const float bias1 = b_ih[jg0 + 1] + b_hh[jg0 + 1];
    __syncthreads();

    for (int t = 1; t <= SLEN; ++t) {
        const unsigned short* hcur = ((t - 1) & 1) ? hB : hA;
        unsigned short* hnxt = (t & 1) ? hB : hA;

        if (t > 1) {   // wait for step t-1 complete (slot t-2); no acquire fence:
            if (wave == 0) {   // h reads below are sc0/sc1 (LLC-coherent).
                const unsigned* s = sig + (size_t)(t - 2) * 64;
                while (!__all(__hip_atomic_load(s + lane, __ATOMIC_RELAXED,
                                                __HIP_MEMORY_SCOPE_AGENT) != 0u))
                    __builtin_amdgcn_s_sleep(1);
            }
            __syncthreads();
        }

        const int bglob = bh * 32 + m * 16 + lr;

        // x loads first (normal cached), then batched coherent h loads
        const float* xp = x + ((size_t)bglob * SLEN + (t - 1)) * NIN + kc * 32 + lg * 8;
        const f32x4 x0 = *(const f32x4*)xp;
        const f32x4 x1 = *(const f32x4*)(xp + 4);

        const unsigned short* hbp = hcur + bglob * 2048 + kc * 512 + lg * 16;
        union HU { u64 q[2]; bf16x8 v; };
        bf16x8 ahh[9], ahl[9];
        #pragma unroll
        for (int ks = 0; ks < 8; ++ks) {
            HU a, b;
            a.q[0] = __hip_atomic_load((const u64*)(hbp + ks * 64),
                                       __ATOMIC_RELAXED, __HIP_MEMORY_SCOPE_AGENT);
            a.q[1] = __hip_atomic_load((const u64*)(hbp + ks * 64 + 4),
                                       __ATOMIC_RELAXED, __HIP_MEMORY_SCOPE_AGENT);
            b.q[0] = __hip_atomic_load((const u64*)(hbp + ks * 64 + 8),
                                       __ATOMIC_RELAXED, __HIP_MEMORY_SCOPE_AGENT);
            b.q[1] = __hip_atomic_load((const u64*)(hbp + ks * 64 + 12),
                                       __ATOMIC_RELAXED, __HIP_MEMORY_SCOPE_AGENT);
            ahh[ks] = a.v; ahl[ks] = b.v;
        }
        {   // x hi/lo split (overlaps in-flight h loads)
            bf16x8 xh, xl;
            #pragma unroll
            for (int e = 0; e < 4; ++e) {
                const unsigned short a = rne_bf16(x0[e]);
                xh[e] = (short)a; xl[e] = (short)rne_bf16(x0[e] - bf2f(a));
                const unsigned short b = rne_bf16(x1[e]);
                xh[4 + e] = (short)b; xl[4 + e] = (short)rne_bf16(x1[e] - bf2f(b));
            }
            ahh[8] = xh; ahl[8] = xl;
        }
        __builtin_amdgcn_sched_barrier(0);   // keep loads batched above MFMAs

        f32x4 acc0 = {0.f, 0.f, 0.f, 0.f}, acc1 = {0.f, 0.f, 0.f, 0.f};
        #pragma unroll
        for (int ks = 0; ks < 9; ++ks) {
            const int wc = (ks < 8) ? (kc * 256 + ks * 32 + lg * 8)
                                    : (1024 + kc * 32 + lg * 8);
            const int ci = (((wc >> 3) ^ (lr & 7)) << 3);
            const bf16x8 wh0 = *(const bf16x8*)&sW[lr * KTOT + ci];
            const bf16x8 wl0 = *(const bf16x8*)&sW[32 * KTOT + lr * KTOT + ci];
            const bf16x8 wh1 = *(const bf16x8*)&sW[(16 + lr) * KTOT + ci];
            const bf16x8 wl1 = *(const bf16x8*)&sW[32 * KTOT + (16 + lr) * KTOT + ci];
            acc0 = __builtin_amdgcn_mfma_f32_16x16x32_bf16(ahh[ks], wh0, acc0, 0, 0, 0);
            acc0 = __builtin_amdgcn_mfma_f32_16x16x32_bf16(ahh[ks], wl0, acc0, 0, 0, 0);
            acc0 = __builtin_amdgcn_mfma_f32_16x16x32_bf16(ahl[ks], wh0, acc0, 0, 0, 0);
            acc1 = __builtin_amdgcn_mfma_f32_16x16x32_bf16(ahh[ks], wh1, acc1, 0, 0, 0);
            acc1 = __builtin_amdgcn_mfma_f32_16x16x32_bf16(ahh[ks], wl1, acc1, 0, 0, 0);
            acc1 = __builtin_amdgcn_mfma_f32_16x16x32_bf16(ahl[ks], wh1, acc1, 0, 0, 0);
        }

        // ---- 2-phase K-reduce in LDS ----
        if (kc < 2) {
            #pragma unroll
            for (int r = 0; r < 4; ++r) {
                red[kc][m * 16 + lg * 4 + r][lr]      = acc0[r];
                red[kc][m * 16 + lg * 4 + r][16 + lr] = acc1[r];
            }
        }
        __syncthreads();
        const float p0 = red[0][b0][jl0] + red[1][b0][jl0];
        const float p1 = red[0][b0][jl0 + 1] + red[1][b0][jl0 + 1];
        __syncthreads();
        if (kc >= 2) {
            #pragma unroll
            for (int r = 0; r < 4; ++r) {
                red[kc - 2][m * 16 + lg * 4 + r][lr]      = acc0[r];
                red[kc - 2][m * 16 + lg * 4 + r][16 + lr] = acc1[r];
            }
        }
        __syncthreads();

        {
            const float s0 = p0 + red[0][b0][jl0] + red[1][b0][jl0] + bias0;
            const float s1 = p1 + red[0][b0][jl0 + 1] + red[1][b0][jl0 + 1] + bias1;
            const float v0 = tanhf(s0);
            const float v1 = tanhf(s1);
            const int bg = bh * 32 + b0;
            const unsigned short h0b = rne_bf16(v0), h1b = rne_bf16(v1);
            const unsigned hpack = (unsigned)h0b | ((unsigned)h1b << 16);
            const unsigned lpack = (unsigned)rne_bf16(v0 - bf2f(h0b))
                                 | ((unsigned)rne_bf16(v1 - bf2f(h1b)) << 16);
            const int ha = bg * 2048 + ((jg0 >> 3) << 4) + (jg0 & 7);
            __hip_atomic_store((unsigned*)(hnxt + ha), hpack,
                               __ATOMIC_RELAXED, __HIP_MEMORY_SCOPE_AGENT);
            __hip_atomic_store((unsigned*)(hnxt + ha + 8), lpack,
                               __ATOMIC_RELAXED, __HIP_MEMORY_SCOPE_AGENT);
            if (t == SLEN) {
                hfp[bg * HID + jg0] = v0;
                hfp[bg * HID + jg0 + 1] = v1;
                out[BSZ * NOUT + bg * HID + jg0] = v0;
                out[BSZ * NOUT + bg * HID + jg0 + 1] = v1;
            }
        }
        __syncthreads();   // drains vmcnt(0): h stores at LLC before flag store
        if (tid == 0) {
            if (t == SLEN)   // RELEASE once: flushes hfp/out (normal stores)
                __hip_atomic_store(sig + (size_t)(t - 1) * 64 + bid, 1u,
                                   __ATOMIC_RELEASE, __HIP_MEMORY_SCOPE_AGENT);
            else
                __hip_atomic_store(sig + (size_t)(t - 1) * 64 + bid, 1u,
                                   __ATOMIC_RELAXED, __HIP_MEMORY_SCOPE_AGENT);
        }
    }

    // ---- head: wait for full h_last (acquire once) ----
    if (wave == 0) {
        const unsigned* s = sig + (size_t)(SLEN - 1) * 64;
        while (!__all(__hip_atomic_load(s + lane, __ATOMIC_RELAXED,
                                        __HIP_MEMORY_SCOPE_AGENT) != 0u))
            __builtin_amdgcn_s_sleep(1);
        __builtin_amdgcn_fence(__ATOMIC_ACQUIRE, "agent");
    }
    __syncthreads();

    // mlp[b][j] = relu(h_last[b] . W1[j] + b1[j]); block: its 32 j x its 32 b
    {
        const int jl = tid & 31, bq = tid >> 5;   // (bq 0..15, jl 0..31)
        const int jg = j0 + jl;
        const f32x4* w1r = (const f32x4*)(W1 + (size_t)jg * HID);
        const int bA = bh * 32 + bq, bB = bA + 16;
        const f32x4* hA4 = (const f32x4*)(hfp + (size_t)bA * HID);
        const f32x4* hB4 = (const f32x4*)(hfp + (size_t)bB * HID);
        float a0 = 0.f, a1 = 0.f;
        for (int k4 = 0; k4 < HID / 4; ++k4) {
            const f32x4 wv = w1r[k4];
            const f32x4 u = hA4[k4], w = hB4[k4];
            a0 += wv[0]*u[0] + wv[1]*u[1] + wv[2]*u[2] + wv[3]*u[3];
            a1 += wv[0]*w[0] + wv[1]*w[1] + wv[2]*w[2] + wv[3]*w[3];
        }
        const float bj = b1[jg];
        mlp[(size_t)bA * HID + jg] = fmaxf(a0 + bj, 0.f);
        mlp[(size_t)bB * HID + jg] = fmaxf(a1 + bj, 0.f);
    }
    __syncthreads();
    if (tid == 0)
        __hip_atomic_store(sig + (size_t)SLEN * 64 + bid, 1u,
                           __ATOMIC_RELEASE, __HIP_MEMORY_SCOPE_AGENT);

    // out[b][o] = mlp[b] . W2[o] + b2[o]  (blocks 0..15, 8192 outputs)
    if (bid < 16) {
        if (wave == 0) {
            const unsigned* s = sig + (size_t)SLEN * 64;
            while (!__all(__hip_atomic_load(s + lane, __ATOMIC_RELAXED,
                                            __HIP_MEMORY_SCOPE_AGENT) != 0u))
                __builtin_amdgcn_s_sleep(1);
            __builtin_amdgcn_fence(__ATOMIC_ACQUIRE, "agent");
        }
        __syncthreads();
        const int g = bid * 512 + tid;
        const int b = g >> 7, o = g & 127;
        const f32x4* w2r = (const f32x4*)(W2 + (size_t)o * HID);
        const f32x4* mr  = (const f32x4*)(mlp + (size_t)b * HID);
        float a = 0.f;
        for (int k4 = 0; k4 < HID / 4; ++k4) {
            const f32x4 wv = w2r[k4], mv = mr[k4];
            a += wv[0]*mv[0] + wv[1]*mv[1] + wv[2]*mv[2] + wv[3]*mv[3];
        }
        out[b * NOUT + o] = a + b2[o];
    }
}

extern "C" void kernel_launch(void* const* d_in, const int* in_sizes, int n_in,
                              void* d_out, int out_size, void* d_ws, size_t ws_size,
                              hipStream_t stream) {
    const float* x    = (const float*)d_in[0];
    const float* h0   = (const float*)d_in[1];
    const float* W_ih = (const float*)d_in[2];
    const float* b_ih = (const float*)d_in[3];
    const float* W_hh = (const float*)d_in[4];
    const float* b_hh = (const float*)d_in[5];
    const float* W1   = (const float*)d_in[6];
    const float* b1   = (const float*)d_in[7];
    const float* W2   = (const float*)d_in[8];
    const float* b2   = (const float*)d_in[9];
    float* out = (float*)d_out;
    unsigned short* wsu = (unsigned short*)d_ws;

    const int nprep = 1024 * KTOT + 65536;   // covers SIG_N zeroing too
    prep<<<(nprep + 255) / 256, 256, 0, stream>>>(W_ih, W_hh, h0, wsu);

    void* args[] = {&x, &b_ih, &b_hh, &W1, &b1, &W2, &b2, &out, &wsu};
    hipLaunchCooperativeKernel(reinterpret_cast<void*>(rnn_mfma),
                               dim3(NBLK), dim3(512), args, 0, stream);
}